// Round 12
// baseline (295.639 us; speedup 1.0000x reference)
//
#include <hip/hip_runtime.h>
#include <math.h>

#define D_   512
#define H_   8
#define DK_  64
#define FF_  2048
#define S_   2048
#define B_   4
#define M_   (B_*S_)     // 8192
#define EPS_ 1e-5f
#define SCLQ 0.1803368801111f   // 0.125 * log2(e): folded into wq/bq at prep

typedef __attribute__((ext_vector_type(8))) short bf16x8;
typedef __attribute__((ext_vector_type(4))) float f32x4;
typedef __attribute__((ext_vector_type(4))) unsigned int u32x4;

__device__ inline unsigned short f2b(float f) {
    unsigned u = __builtin_bit_cast(unsigned, f);
    unsigned r = (u + 0x7FFFu + ((u >> 16) & 1u)) >> 16;
    return (unsigned short)r;
}
__device__ inline float b2f(unsigned short u) {
    return __builtin_bit_cast(float, (unsigned)u << 16);
}
// pack hi16(p0) low half, hi16(p1) high half (truncating bf16 pair)
__device__ inline unsigned packbf(float p0, float p1) {
    return (__builtin_bit_cast(unsigned, p1) & 0xFFFF0000u) |
           (__builtin_bit_cast(unsigned, p0) >> 16);
}

// async 16B global->LDS. LDS dest must be wave-uniform base + lane*16.
__device__ __forceinline__ void async_cp16(const void* g, void* l) {
    __builtin_amdgcn_global_load_lds(
        (const __attribute__((address_space(1))) unsigned int*)g,
        (__attribute__((address_space(3))) unsigned int*)l, 16, 0, 0);
}

// ---------------------------------------------------------------------------
// Unified preprocessing (1 dispatch, 5120 blocks).
// ---------------------------------------------------------------------------
__global__ __launch_bounds__(256)
void prep_kernel(const float* __restrict__ x,
                 const float* __restrict__ wq, const float* __restrict__ wk,
                 const float* __restrict__ wv, const float* __restrict__ wo,
                 const float* __restrict__ bq, const float* __restrict__ bk,
                 const float* __restrict__ bv,
                 const float* __restrict__ w1, const float* __restrict__ w2,
                 unsigned short* __restrict__ xb, unsigned short* __restrict__ wqkvt,
                 unsigned short* __restrict__ wot, unsigned short* __restrict__ w1t,
                 unsigned short* __restrict__ w2t, float* __restrict__ bqkv)
{
    __shared__ float L[32][33];
    const int bid = blockIdx.x;
    const int tid = threadIdx.x;

    if (bid < 2048) {                       // x -> xb
        const int i = (bid * 256 + tid) * 8;
        const float4 a = *(const float4*)(x + i);
        const float4 b = *(const float4*)(x + i + 4);
        bf16x8 v;
        v[0] = (short)f2b(a.x); v[1] = (short)f2b(a.y);
        v[2] = (short)f2b(a.z); v[3] = (short)f2b(a.w);
        v[4] = (short)f2b(b.x); v[5] = (short)f2b(b.y);
        v[6] = (short)f2b(b.z); v[7] = (short)f2b(b.w);
        *(bf16x8*)(xb + i) = v;
        return;
    }

    const float* w; unsigned short* wt; int K, N, k0, n0; float scl = 1.f;
    if (bid < 3072) {
        const int z = (bid - 2048) >> 8;
        const int r = (bid - 2048) & 255;
        n0 = (r & 15) * 32; k0 = (r >> 4) * 32; K = 512; N = 512;
        w  = (z == 0) ? wq : (z == 1) ? wk : (z == 2) ? wv : wo;
        wt = (z < 3) ? (wqkvt + (size_t)z * 512 * 512) : wot;
        if (z == 0) scl = SCLQ;
        if (z < 3 && r == 0) {
            const float* bsrc = (z == 0) ? bq : (z == 1) ? bk : bv;
            const float bscl  = (z == 0) ? SCLQ : 1.f;
            bqkv[z * 512 + tid]       = bsrc[tid] * bscl;
            bqkv[z * 512 + 256 + tid] = bsrc[256 + tid] * bscl;
        }
    } else if (bid < 4096) {
        const int r = bid - 3072;
        n0 = (r & 63) * 32; k0 = (r >> 6) * 32; K = 512; N = 2048;
        w = w1; wt = w1t;
    } else {
        const int r = bid - 4096;
        n0 = (r & 15) * 32; k0 = (r >> 4) * 32; K = 2048; N = 512;
        w = w2; wt = w2t;
    }

    const int xx = tid & 31, y = tid >> 5;
#pragma unroll
    for (int i = 0; i < 4; i++)
        L[y + i * 8][xx] = w[(size_t)(k0 + y + i * 8) * N + n0 + xx] * scl;
    __syncthreads();
#pragma unroll
    for (int i = 0; i < 4; i++)
        wt[(size_t)(n0 + y + i * 8) * K + k0 + xx] = f2b(L[xx][y + i * 8]);
}

// ---------------------------------------------------------------------------
// bf16 MFMA GEMM, double-buffered (prefetch + partial vmcnt + raw s_barrier).
// RESADD: 0 none, 1 fp32 residual, 2 bf16 residual (C-layout indexed).
// ---------------------------------------------------------------------------
template<int WR, int WC, int MT, int NT, int OUTB, int RELU, int RESADD, int HASBIAS>
__global__ __launch_bounds__(256)
void gemm_bf16(const unsigned short* __restrict__ A, const unsigned short* __restrict__ Bt,
               const float* __restrict__ bias, const void* __restrict__ RES,
               void* __restrict__ Cv, int K, int lda, int ldb, int ldc)
{
    constexpr int BM = WR * MT * 16;
    constexpr int BN = WC * NT * 16;
    constexpr int CA = BM / 64;
    constexpr int CB = BN / 64;
    __shared__ unsigned short As[2][BM * 32];
    __shared__ unsigned short Bs[2][BN * 32];

    const int tid  = threadIdx.x;
    const int lane = tid & 63;
    const int w    = tid >> 6;
    const int wr   = w / WC, wc = w % WC;
    const int quad = lane >> 4;
    const int l15  = lane & 15;
    const int n0   = blockIdx.x * BN;
    const int m0   = blockIdx.y * BM;

    f32x4 acc[MT][NT];
#pragma unroll
    for (int i = 0; i < MT; i++)
#pragma unroll
        for (int j = 0; j < NT; j++) acc[i][j] = (f32x4){0.f, 0.f, 0.f, 0.f};

    auto stage = [&](int k0, int bufi) {
#pragma unroll
        for (int i = 0; i < CA; i++) {
            const int c = tid + i * 256;
            async_cp16(&A[(size_t)(m0 + (c >> 2)) * lda + k0 + (c & 3) * 8], &As[bufi][c * 8]);
        }
#pragma unroll
        for (int i = 0; i < CB; i++) {
            const int c = tid + i * 256;
            async_cp16(&Bt[(size_t)(n0 + (c >> 2)) * ldb + k0 + (c & 3) * 8], &Bs[bufi][c * 8]);
        }
    };

    stage(0, 0);
    const int niter = K >> 5;
    for (int ii = 0; ii < niter; ii++) {
        const int knext = (ii + 1 < niter) ? (ii + 1) * 32 : 0;
        stage(knext, (ii + 1) & 1);
        __builtin_amdgcn_s_waitcnt(0x0f70 | (CA + CB));
        __builtin_amdgcn_s_barrier();

        const unsigned short* Ac = &As[ii & 1][0];
        const unsigned short* Bc = &Bs[ii & 1][0];
        bf16x8 af[MT], bfr[NT];
#pragma unroll
        for (int t = 0; t < MT; t++)
            af[t]  = *(const bf16x8*)&Ac[(wr * MT * 16 + t * 16 + l15) * 32 + quad * 8];
#pragma unroll
        for (int t = 0; t < NT; t++)
            bfr[t] = *(const bf16x8*)&Bc[(wc * NT * 16 + t * 16 + l15) * 32 + quad * 8];
#pragma unroll
        for (int mt = 0; mt < MT; mt++)
#pragma unroll
            for (int nt = 0; nt < NT; nt++)
                acc[mt][nt] = __builtin_amdgcn_mfma_f32_16x16x32_bf16(
                    af[mt], bfr[nt], acc[mt][nt], 0, 0, 0);
        __builtin_amdgcn_s_barrier();
    }

    // epilogue: C/D layout col=lane&15, row=quad*4+reg
#pragma unroll
    for (int mt = 0; mt < MT; mt++) {
        const int rowb = m0 + wr * MT * 16 + mt * 16 + quad * 4;
#pragma unroll
        for (int nt = 0; nt < NT; nt++) {
            const int col = n0 + wc * NT * 16 + nt * 16 + l15;
            const float bv = HASBIAS ? bias[col] : 0.f;
#pragma unroll
            for (int r = 0; r < 4; r++) {
                const size_t idx = (size_t)(rowb + r) * ldc + col;
                float v = acc[mt][nt][r] + bv;
                if (RESADD == 1) v += ((const float*)RES)[idx];
                if (RESADD == 2) v += b2f(((const unsigned short*)RES)[idx]);
                if (RELU)   v = fmaxf(v, 0.f);
                if (OUTB) ((unsigned short*)Cv)[idx] = f2b(v);
                else      ((float*)Cv)[idx] = v;
            }
        }
    }
}

// ---------------------------------------------------------------------------
// V transpose: qkv v-part [s][dk] per (b,h) -> vt [(b*8+h)*64+dk][s] bf16.
// ---------------------------------------------------------------------------
__global__ __launch_bounds__(256)
void vtrans(const unsigned short* __restrict__ qkv, unsigned short* __restrict__ vt)
{
    __shared__ unsigned short L[64][72];
    const int s0 = blockIdx.x * 64;
    const int bh = blockIdx.y;
    const int b  = bh >> 3, hh = bh & 7;
    const int tid = threadIdx.x;
    const unsigned short* src = qkv + (size_t)(b * S_) * 1536 + 1024 + hh * 64;
#pragma unroll
    for (int i = 0; i < 2; i++) {
        const int c = tid + i * 256;
        const int r = c >> 3, sub = (c & 7) * 8;
        *(bf16x8*)&L[r][sub] = *(const bf16x8*)(src + (size_t)(s0 + r) * 1536 + sub);
    }
    __syncthreads();
    const int dk = tid >> 2;
    const int sc = (tid & 3) * 16;
    bf16x8 t0, t1;
#pragma unroll
    for (int j = 0; j < 8; j++) t0[j] = (short)L[sc + j][dk];
#pragma unroll
    for (int j = 0; j < 8; j++) t1[j] = (short)L[sc + 8 + j][dk];
    unsigned short* dst = vt + (size_t)(bh * 64 + dk) * S_ + s0 + sc;
    *(bf16x8*)(dst)     = t0;
    *(bf16x8*)(dst + 8) = t1;
}

// ---------------------------------------------------------------------------
// Causal flash attention, register-P + 2x K/V-FRAGMENT REUSE.
// BQ=128: 4 waves, each owns two 16-row q-tiles (mt=0: qb*128+w*16,
// mt=1: qb*128+64+w*16). KB=64 double-buffered staging, raw barriers.
// Every K/V fragment read feeds BOTH mt tiles -> DS-pipe traffic per unit
// work halves (the measured bottleneck: r11 occupancy up + VALU down with
// no time change; MFMA 14%, HBM 5%).
// S^T trick (A=K,B=Q) + cross-quad shuffle assembly of PV A-fragment.
// Diagonal peeled twice: kb=2qb (mt0 masked, mt1 full), kb=2qb+1 (mt1 masked).
// Grid 512, complement-ordered qb for statistical per-CU balance (sums 34).
// ---------------------------------------------------------------------------
__global__ __launch_bounds__(256, 2)
void attn_mfma(const unsigned short* __restrict__ qkv,
               const unsigned short* __restrict__ vt,
               unsigned short* __restrict__ ctx)
{
    __shared__ unsigned short Ks[2][64 * 64];   // [kr][d], chunk^=(kr&7)
    __shared__ unsigned short Vs[2][64 * 64];   // [dk][kr], chunk^=(dk&7)

    const int tid  = threadIdx.x;
    const int lane = tid & 63;
    const int w    = tid >> 6;
    const int quad = lane >> 4;
    const int l15  = lane & 15;
    const int g    = blockIdx.x >> 5;
    const int qb   = (g < 8) ? (15 - g) : (g - 8); // complement order: CU pairs sum 15
    const int bh   = blockIdx.x & 31;
    const int b    = bh >> 3, hh = bh & 7;

    const unsigned short* qbase = qkv + (size_t)(b * S_) * 1536 + hh * 64;
    const unsigned short* kbase = qbase + 512;
    const unsigned short* vtb   = vt + (size_t)bh * 64 * S_;

    const int srcA  = 32 * (quad & 1) + l15;    // shuffle sources (same l15 = same q)
    const int srcB  = srcA + 16;
    const bool selHi = (quad >> 1) != 0;

    bf16x8 ones;
#pragma unroll
    for (int j = 0; j < 8; j++) ones[j] = (short)0x3F80;

    auto stage = [&](int kb, int bufi) {
        unsigned short* kd = &Ks[bufi][0];
        unsigned short* vd = &Vs[bufi][0];
#pragma unroll
        for (int i = 0; i < 2; i++) {
            const int c = tid + i * 256;
            const int row = c >> 3;
            const int l = (c & 7) ^ (row & 7);
            async_cp16(kbase + (size_t)(kb * 64 + row) * 1536 + l * 8, kd + c * 8);
            async_cp16(vtb + (size_t)row * S_ + kb * 64 + l * 8, vd + c * 8);
        }
    };

    // Q fragments for both mt tiles
    bf16x8 qf[2][2];
#pragma unroll
    for (int mt = 0; mt < 2; mt++) {
        const unsigned short* qr = qbase + (size_t)(qb * 128 + mt * 64 + w * 16 + l15) * 1536;
        qf[mt][0] = *(const bf16x8*)(qr + quad * 8);
        qf[mt][1] = *(const bf16x8*)(qr + 32 + quad * 8);
    }

    f32x4 Oacc[2][5];
#pragma unroll
    for (int mt = 0; mt < 2; mt++)
#pragma unroll
        for (int i = 0; i < 5; i++) Oacc[mt][i] = (f32x4){0.f, 0.f, 0.f, 0.f};

    stage(0, 0);

    // assemble PV A-fragment for tile-pair kc from packed S^T regs
    auto assemble = [&](const unsigned pk[4][2], int kc) -> bf16x8 {
        const unsigned tA0 = __shfl(pk[kc * 2][0],     srcA, 64);
        const unsigned tA1 = __shfl(pk[kc * 2][1],     srcA, 64);
        const unsigned tB0 = __shfl(pk[kc * 2 + 1][0], srcA, 64);
        const unsigned tB1 = __shfl(pk[kc * 2 + 1][1], srcA, 64);
        const unsigned uA0 = __shfl(pk[kc * 2][0],     srcB, 64);
        const unsigned uA1 = __shfl(pk[kc * 2][1],     srcB, 64);
        const unsigned uB0 = __shfl(pk[kc * 2 + 1][0], srcB, 64);
        const unsigned uB1 = __shfl(pk[kc * 2 + 1][1], srcB, 64);
        u32x4 a;
        a[0] = selHi ? tB0 : tA0;
        a[1] = selHi ? tB1 : tA1;
        a[2] = selHi ? uB0 : uA0;
        a[3] = selHi ? uB1 : uA1;
        return __builtin_bit_cast(bf16x8, a);
    };

    const int nmain = 2 * qb;                   // unmasked iterations

    // ---- main loop: both mt unmasked, K/V fragments shared
    for (int kb = 0; kb < nmain; kb++) {
        stage(kb + 1, (kb + 1) & 1);
        __builtin_amdgcn_s_waitcnt(0x0F74);     // vmcnt(4)
        __builtin_amdgcn_s_barrier();
        const unsigned short* Kc = &Ks[kb & 1][0];
        const unsigned short* Vc = &Vs[kb & 1][0];

        f32x4 st[2][4];
#pragma unroll
        for (int mt = 0; mt < 2; mt++)
#pragma unroll
            for (int nt = 0; nt < 4; nt++) st[mt][nt] = (f32x4){0.f, 0.f, 0.f, 0.f};
#pragma unroll
        for (int kc = 0; kc < 2; kc++)
#pragma unroll
            for (int nt = 0; nt < 4; nt++) {
                const int phys = (kc * 4 + quad) ^ (l15 & 7);
                const bf16x8 kf = *(const bf16x8*)&Kc[(nt * 16 + l15) * 64 + phys * 8];
                st[0][nt] = __builtin_amdgcn_mfma_f32_16x16x32_bf16(kf, qf[0][kc], st[0][nt], 0, 0, 0);
                st[1][nt] = __builtin_amdgcn_mfma_f32_16x16x32_bf16(kf, qf[1][kc], st[1][nt], 0, 0, 0);
            }

        unsigned pk[2][4][2];
#pragma unroll
        for (int mt = 0; mt < 2; mt++)
#pragma unroll
            for (int nt = 0; nt < 4; nt++) {
                pk[mt][nt][0] = packbf(exp2f(st[mt][nt][0]), exp2f(st[mt][nt][1]));
                pk[mt][nt][1] = packbf(exp2f(st[mt][nt][2]), exp2f(st[mt][nt][3]));
            }

#pragma unroll
        for (int kc = 0; kc < 2; kc++) {
            const bf16x8 af0 = assemble(pk[0], kc);
            const bf16x8 af1 = assemble(pk[1], kc);
#pragma unroll
            for (int nt = 0; nt < 4; nt++) {
                const int phys = (kc * 4 + quad) ^ (l15 & 7);
                const bf16x8 vf = *(const bf16x8*)&Vc[(nt * 16 + l15) * 64 + phys * 8];
                Oacc[0][nt] = __builtin_amdgcn_mfma_f32_16x16x32_bf16(af0, vf, Oacc[0][nt], 0, 0, 0);
                Oacc[1][nt] = __builtin_amdgcn_mfma_f32_16x16x32_bf16(af1, vf, Oacc[1][nt], 0, 0, 0);
            }
            Oacc[0][4] = __builtin_amdgcn_mfma_f32_16x16x32_bf16(af0, ones, Oacc[0][4], 0, 0, 0);
            Oacc[1][4] = __builtin_amdgcn_mfma_f32_16x16x32_bf16(af1, ones, Oacc[1][4], 0, 0, 0);
        }
        __builtin_amdgcn_s_barrier();
    }

    const int rhs  = w * 16 + l15;              // local q row within 64-tile
    const int kc_d = (w >> 1) + 1;

    // ---- peel A (kb = 2qb): mt0 diagonal-masked, mt1 full
    {
        stage(nmain + 1, (nmain + 1) & 1);
        __builtin_amdgcn_s_waitcnt(0x0F74);
        __builtin_amdgcn_s_barrier();
        const unsigned short* Kc = &Ks[nmain & 1][0];
        const unsigned short* Vc = &Vs[nmain & 1][0];

        f32x4 st[2][4];
#pragma unroll
        for (int mt = 0; mt < 2; mt++)
#pragma unroll
            for (int nt = 0; nt < 4; nt++) st[mt][nt] = (f32x4){0.f, 0.f, 0.f, 0.f};
#pragma unroll
        for (int kc = 0; kc < 2; kc++)
#pragma unroll
            for (int nt = 0; nt < 4; nt++) {
                const int phys = (kc * 4 + quad) ^ (l15 & 7);
                const bf16x8 kf = *(const bf16x8*)&Kc[(nt * 16 + l15) * 64 + phys * 8];
                if (nt <= w)
                    st[0][nt] = __builtin_amdgcn_mfma_f32_16x16x32_bf16(kf, qf[0][kc], st[0][nt], 0, 0, 0);
                st[1][nt] = __builtin_amdgcn_mfma_f32_16x16x32_bf16(kf, qf[1][kc], st[1][nt], 0, 0, 0);
            }

        unsigned pk[2][4][2];
#pragma unroll
        for (int nt = 0; nt < 4; nt++) {
            const int kb0 = nt * 16 + quad * 4;
            float p[4];
#pragma unroll
            for (int r = 0; r < 4; r++) {
                float s = st[0][nt][r];
                if (kb0 + r > rhs) s = -1.0e9f;
                p[r] = exp2f(s);
            }
            pk[0][nt][0] = packbf(p[0], p[1]);
            pk[0][nt][1] = packbf(p[2], p[3]);
            pk[1][nt][0] = packbf(exp2f(st[1][nt][0]), exp2f(st[1][nt][1]));
            pk[1][nt][1] = packbf(exp2f(st[1][nt][2]), exp2f(st[1][nt][3]));
        }

#pragma unroll
        for (int kc = 0; kc < 2; kc++) {
            const bf16x8 af1 = assemble(pk[1], kc);
#pragma unroll
            for (int nt = 0; nt < 4; nt++) {
                const int phys = (kc * 4 + quad) ^ (l15 & 7);
                const bf16x8 vf = *(const bf16x8*)&Vc[(nt * 16 + l15) * 64 + phys * 8];
                Oacc[1][nt] = __builtin_amdgcn_mfma_f32_16x16x32_bf16(af1, vf, Oacc[1][nt], 0, 0, 0);
            }
            Oacc[1][4] = __builtin_amdgcn_mfma_f32_16x16x32_bf16(af1, ones, Oacc[1][4], 0, 0, 0);
            if (kc < kc_d) {
                const bf16x8 af0 = assemble(pk[0], kc);
#pragma unroll
                for (int nt = 0; nt < 4; nt++) {
                    const int phys = (kc * 4 + quad) ^ (l15 & 7);
                    const bf16x8 vf = *(const bf16x8*)&Vc[(nt * 16 + l15) * 64 + phys * 8];
                    Oacc[0][nt] = __builtin_amdgcn_mfma_f32_16x16x32_bf16(af0, vf, Oacc[0][nt], 0, 0, 0);
                }
                Oacc[0][4] = __builtin_amdgcn_mfma_f32_16x16x32_bf16(af0, ones, Oacc[0][4], 0, 0, 0);
            }
        }
        __builtin_amdgcn_s_barrier();
    }

    // ---- peel B (kb = 2qb+1): mt1 diagonal-masked only
    {
        stage(0, nmain & 1);                    // dummy prefetch (uniform vmcnt)
        __builtin_amdgcn_s_waitcnt(0x0F74);
        __builtin_amdgcn_s_barrier();
        const unsigned short* Kc = &Ks[(nmain + 1) & 1][0];
        const unsigned short* Vc = &Vs[(nmain + 1) & 1][0];

        f32x4 st[4];
#pragma unroll
        for (int nt = 0; nt < 4; nt++) st[nt] = (f32x4){0.f, 0.f, 0.f, 0.f};
#pragma unroll
        for (int kc = 0; kc < 2; kc++)
#pragma unroll
            for (int nt = 0; nt < 4; nt++) {
                if (nt > w) continue;
                const int phys = (kc * 4 + quad) ^ (l15 & 7);
                const bf16x8 kf = *(const bf16x8*)&Kc[(nt * 16 + l15) * 64 + phys * 8];
                st[nt] = __builtin_amdgcn_mfma_f32_16x16x32_bf16(kf, qf[1][kc], st[nt], 0, 0, 0);
            }

        unsigned pk[4][2];
#pragma unroll
        for (int nt = 0; nt < 4; nt++) {
            const int kb0 = nt * 16 + quad * 4;
            float p[4];
#pragma unroll
            for (int r = 0; r < 4; r++) {
                float s = st[nt][r];
                if (kb0 + r > rhs) s = -1.0e9f;
                p[r] = exp2f(s);
            }
            pk[nt][0] = packbf(p[0], p[1]);
            pk[nt][1] = packbf(p[2], p[3]);
        }

#pragma unroll
        for (int kc = 0; kc < 2; kc++) {
            if (kc < kc_d) {
                const bf16x8 af = assemble(pk, kc);
#pragma unroll
                for (int nt = 0; nt < 4; nt++) {
                    const int phys = (kc * 4 + quad) ^ (l15 & 7);
                    const bf16x8 vf = *(const bf16x8*)&Vc[(nt * 16 + l15) * 64 + phys * 8];
                    Oacc[1][nt] = __builtin_amdgcn_mfma_f32_16x16x32_bf16(af, vf, Oacc[1][nt], 0, 0, 0);
                }
                Oacc[1][4] = __builtin_amdgcn_mfma_f32_16x16x32_bf16(af, ones, Oacc[1][4], 0, 0, 0);
            }
        }
    }

    // ---- normalize + write ctx bf16 (O rows q=quad*4+r, cols dk)
    unsigned short* cb = ctx + (size_t)(b * S_) * 512 + hh * 64;
#pragma unroll
    for (int mt = 0; mt < 2; mt++) {
        const int orow = qb * 128 + mt * 64 + w * 16 + quad * 4;
#pragma unroll
        for (int r = 0; r < 4; r++) {
            const float inv = 1.f / Oacc[mt][4][r];
#pragma unroll
            for (int nt = 0; nt < 4; nt++)
                cb[(size_t)(orow + r) * 512 + nt * 16 + l15] = f2b(Oacc[mt][nt][r] * inv);
        }
    }
}

// ---------------------------------------------------------------------------
// LayerNorm: WF -> fp32 out, WB -> bf16 out. 1 wave/row.
// ---------------------------------------------------------------------------
template<int WF, int WB>
__global__ __launch_bounds__(256)
void ln_kernel(const float* __restrict__ s, const float* __restrict__ g,
               const float* __restrict__ be, float* __restrict__ out,
               unsigned short* __restrict__ outb)
{
    const int wave = threadIdx.x >> 6;
    const int lane = threadIdx.x & 63;
    const int row  = blockIdx.x * 4 + wave;
    const float* ps = s + (size_t)row * D_;
    const int c0 = lane * 4;

    float v[8];
    {
        const float4 a0 = *(const float4*)(ps + c0);
        const float4 a1 = *(const float4*)(ps + c0 + 256);
        v[0] = a0.x; v[1] = a0.y; v[2] = a0.z; v[3] = a0.w;
        v[4] = a1.x; v[5] = a1.y; v[6] = a1.z; v[7] = a1.w;
    }

    float sum = 0.f;
#pragma unroll
    for (int i = 0; i < 8; i++) sum += v[i];
#pragma unroll
    for (int m = 1; m < 64; m <<= 1) sum += __shfl_xor(sum, m);
    const float mu = sum * (1.f / D_);

    float sq = 0.f;
#pragma unroll
    for (int i = 0; i < 8; i++) { const float d = v[i] - mu; sq += d * d; }
#pragma unroll
    for (int m = 1; m < 64; m <<= 1) sq += __shfl_xor(sq, m);
    const float rstd = rsqrtf(sq * (1.f / D_) + EPS_);

    const float4 g0 = *(const float4*)(g + c0);
    const float4 b0 = *(const float4*)(be + c0);
    const float4 g1 = *(const float4*)(g + c0 + 256);
    const float4 b1 = *(const float4*)(be + c0 + 256);

    float o[8];
    o[0] = (v[0] - mu) * rstd * g0.x + b0.x;
    o[1] = (v[1] - mu) * rstd * g0.y + b0.y;
    o[2] = (v[2] - mu) * rstd * g0.z + b0.z;
    o[3] = (v[3] - mu) * rstd * g0.w + b0.w;
    o[4] = (v[4] - mu) * rstd * g1.x + b1.x;
    o[5] = (v[5] - mu) * rstd * g1.y + b1.y;
    o[6] = (v[6] - mu) * rstd * g1.z + b1.z;
    o[7] = (v[7] - mu) * rstd * g1.w + b1.w;

    if (WF) {
        *(float4*)(out + (size_t)row * D_ + c0)       = *(float4*)&o[0];
        *(float4*)(out + (size_t)row * D_ + c0 + 256) = *(float4*)&o[4];
    }
    if (WB) {
        short4 vb0 = (short4){(short)f2b(o[0]), (short)f2b(o[1]), (short)f2b(o[2]), (short)f2b(o[3])};
        short4 vb1 = (short4){(short)f2b(o[4]), (short)f2b(o[5]), (short)f2b(o[6]), (short)f2b(o[7])};
        *(short4*)(outb + (size_t)row * D_ + c0)       = vb0;
        *(short4*)(outb + (size_t)row * D_ + c0 + 256) = vb1;
    }
}

// ---------------------------------------------------------------------------
extern "C" void kernel_launch(void* const* d_in, const int* in_sizes, int n_in,
                              void* d_out, int out_size, void* d_ws, size_t ws_size,
                              hipStream_t stream)
{
    const float* x  = (const float*)d_in[0];
    const float* wq = (const float*)d_in[2];
    const float* bq = (const float*)d_in[3];
    const float* wk = (const float*)d_in[4];
    const float* bk = (const float*)d_in[5];
    const float* wv = (const float*)d_in[6];
    const float* bv = (const float*)d_in[7];
    const float* wo = (const float*)d_in[8];
    const float* bo = (const float*)d_in[9];
    const float* w1 = (const float*)d_in[10];
    const float* b1 = (const float*)d_in[11];
    const float* w2 = (const float*)d_in[12];
    const float* b2 = (const float*)d_in[13];
    const float* g1 = (const float*)d_in[14];
    const float* be1= (const float*)d_in[15];
    const float* g2 = (const float*)d_in[16];
    const float* be2= (const float*)d_in[17];
    float* out = (float*)d_out;

    const size_t MB = 1048576;
    char* w8 = (char*)d_ws;
    unsigned short* wqkvt = (unsigned short*)(w8 + 0);            // 1536x512 bf16
    unsigned short* wot   = (unsigned short*)(w8 + 1572864);      // 512x512
    unsigned short* w1t   = (unsigned short*)(w8 + 2097152);      // 2048x512
    unsigned short* w2t   = (unsigned short*)(w8 + 4194304);      // 512x2048
    float*          bqkv  = (float*)(w8 + 6291456);               // 1536 f32
    unsigned short* qkv   = (unsigned short*)(w8 + 8 * MB);       // 24 MB (later ffn1b)
    unsigned short* ffn1b = qkv;
    unsigned short* xb    = (unsigned short*)(w8 + 40 * MB);      // 8 MB (later ctx)
    unsigned short* ctx   = xb;
    unsigned short* vt    = (unsigned short*)(w8 + 48 * MB);      // 8 MB (later hb)
    unsigned short* hb    = vt;
    float*          pre   = (float*)(w8 + 56 * MB);               // 16 MB

    const dim3 blk(256);

    // unified preprocessing (1 dispatch)
    prep_kernel<<<dim3(5120), blk, 0, stream>>>(
        x, wq, wk, wv, wo, bq, bk, bv, w1, w2, xb, wqkvt, wot, w1t, w2t, bqkv);

    // qkv = xb @ [wq*SCLQ|wk|wv] + b -> bf16 [M][1536]
    gemm_bf16<2,2,4,4,1,0,0,1><<<dim3(12, 64), blk, 0, stream>>>(
        xb, wqkvt, bqkv, nullptr, qkv, 512, 512, 512, 1536);

    vtrans<<<dim3(32, 32), blk, 0, stream>>>(qkv, vt);

    // causal flash attention (register-P, 2x K/V reuse, BQ=128) -> ctx bf16
    attn_mfma<<<dim3(512), blk, 0, stream>>>(qkv, vt, ctx);

    // pre = x + ctx @ wo + bo (fp32 residual)
    gemm_bf16<2,2,2,4,0,0,1,1><<<dim3(4, 128), blk, 0, stream>>>(
        ctx, wot, bo, x, pre, 512, 512, 512, 512);

    // hb = LN(pre) bf16 only
    ln_kernel<0,1><<<dim3(M_ / 4), blk, 0, stream>>>(pre, g1, be1, nullptr, hb);

    // ffn1 = relu(hb @ w1 + b1) -> bf16 [M][2048]
    gemm_bf16<2,2,4,4,1,1,0,1><<<dim3(16, 64), blk, 0, stream>>>(
        hb, w1t, b1, nullptr, ffn1b, 512, 512, 512, 2048);

    // pre = hb + ffn1 @ w2 + b2 (bf16 residual)
    gemm_bf16<2,2,2,4,0,0,2,1><<<dim3(4, 128), blk, 0, stream>>>(
        ffn1b, w2t, b2, hb, pre, 2048, 2048, 2048, 512);

    // out = LN(pre)
    ln_kernel<1,0><<<dim3(M_ / 4), blk, 0, stream>>>(pre, g2, be2, out, nullptr);
}

// Round 13
// 293.445 us; speedup vs baseline: 1.0075x; 1.0075x over previous
//
#include <hip/hip_runtime.h>
#include <math.h>

#define D_   512
#define H_   8
#define DK_  64
#define FF_  2048
#define S_   2048
#define B_   4
#define M_   (B_*S_)     // 8192
#define EPS_ 1e-5f
#define SCLQ 0.1803368801111f   // 0.125 * log2(e): folded into wq/bq at prep

typedef __attribute__((ext_vector_type(8))) short bf16x8;
typedef __attribute__((ext_vector_type(4))) float f32x4;
typedef __attribute__((ext_vector_type(4))) unsigned int u32x4;

__device__ inline unsigned short f2b(float f) {
    unsigned u = __builtin_bit_cast(unsigned, f);
    unsigned r = (u + 0x7FFFu + ((u >> 16) & 1u)) >> 16;
    return (unsigned short)r;
}
__device__ inline float b2f(unsigned short u) {
    return __builtin_bit_cast(float, (unsigned)u << 16);
}
// pack hi16(p0) low half, hi16(p1) high half (truncating bf16 pair)
__device__ inline unsigned packbf(float p0, float p1) {
    return (__builtin_bit_cast(unsigned, p1) & 0xFFFF0000u) |
           (__builtin_bit_cast(unsigned, p0) >> 16);
}

// async 16B global->LDS. LDS dest must be wave-uniform base + lane*16.
__device__ __forceinline__ void async_cp16(const void* g, void* l) {
    __builtin_amdgcn_global_load_lds(
        (const __attribute__((address_space(1))) unsigned int*)g,
        (__attribute__((address_space(3))) unsigned int*)l, 16, 0, 0);
}

// ---------------------------------------------------------------------------
// Unified preprocessing (1 dispatch, 5120 blocks).
// ---------------------------------------------------------------------------
__global__ __launch_bounds__(256)
void prep_kernel(const float* __restrict__ x,
                 const float* __restrict__ wq, const float* __restrict__ wk,
                 const float* __restrict__ wv, const float* __restrict__ wo,
                 const float* __restrict__ bq, const float* __restrict__ bk,
                 const float* __restrict__ bv,
                 const float* __restrict__ w1, const float* __restrict__ w2,
                 unsigned short* __restrict__ xb, unsigned short* __restrict__ wqkvt,
                 unsigned short* __restrict__ wot, unsigned short* __restrict__ w1t,
                 unsigned short* __restrict__ w2t, float* __restrict__ bqkv)
{
    __shared__ float L[32][33];
    const int bid = blockIdx.x;
    const int tid = threadIdx.x;

    if (bid < 2048) {                       // x -> xb
        const int i = (bid * 256 + tid) * 8;
        const float4 a = *(const float4*)(x + i);
        const float4 b = *(const float4*)(x + i + 4);
        bf16x8 v;
        v[0] = (short)f2b(a.x); v[1] = (short)f2b(a.y);
        v[2] = (short)f2b(a.z); v[3] = (short)f2b(a.w);
        v[4] = (short)f2b(b.x); v[5] = (short)f2b(b.y);
        v[6] = (short)f2b(b.z); v[7] = (short)f2b(b.w);
        *(bf16x8*)(xb + i) = v;
        return;
    }

    const float* w; unsigned short* wt; int K, N, k0, n0; float scl = 1.f;
    if (bid < 3072) {
        const int z = (bid - 2048) >> 8;
        const int r = (bid - 2048) & 255;
        n0 = (r & 15) * 32; k0 = (r >> 4) * 32; K = 512; N = 512;
        w  = (z == 0) ? wq : (z == 1) ? wk : (z == 2) ? wv : wo;
        wt = (z < 3) ? (wqkvt + (size_t)z * 512 * 512) : wot;
        if (z == 0) scl = SCLQ;
        if (z < 3 && r == 0) {
            const float* bsrc = (z == 0) ? bq : (z == 1) ? bk : bv;
            const float bscl  = (z == 0) ? SCLQ : 1.f;
            bqkv[z * 512 + tid]       = bsrc[tid] * bscl;
            bqkv[z * 512 + 256 + tid] = bsrc[256 + tid] * bscl;
        }
    } else if (bid < 4096) {
        const int r = bid - 3072;
        n0 = (r & 63) * 32; k0 = (r >> 6) * 32; K = 512; N = 2048;
        w = w1; wt = w1t;
    } else {
        const int r = bid - 4096;
        n0 = (r & 15) * 32; k0 = (r >> 4) * 32; K = 2048; N = 512;
        w = w2; wt = w2t;
    }

    const int xx = tid & 31, y = tid >> 5;
#pragma unroll
    for (int i = 0; i < 4; i++)
        L[y + i * 8][xx] = w[(size_t)(k0 + y + i * 8) * N + n0 + xx] * scl;
    __syncthreads();
#pragma unroll
    for (int i = 0; i < 4; i++)
        wt[(size_t)(n0 + y + i * 8) * K + k0 + xx] = f2b(L[xx][y + i * 8]);
}

// ---------------------------------------------------------------------------
// bf16 MFMA GEMM, double-buffered (prefetch + partial vmcnt + raw s_barrier).
// RESADD: 0 none, 1 fp32 residual, 2 bf16 residual (C-layout indexed).
// QKVW: blocks with n0>=1024 are V-projection columns -> write TRANSPOSED
// into vt [(b*8+h)*64+dk][s] (fuses the old vtrans kernel); q/k cols use ldc.
// ---------------------------------------------------------------------------
template<int WR, int WC, int MT, int NT, int OUTB, int RELU, int RESADD, int HASBIAS, int QKVW>
__global__ __launch_bounds__(256)
void gemm_bf16(const unsigned short* __restrict__ A, const unsigned short* __restrict__ Bt,
               const float* __restrict__ bias, const void* __restrict__ RES,
               void* __restrict__ Cv, unsigned short* __restrict__ vtout,
               int K, int lda, int ldb, int ldc)
{
    constexpr int BM = WR * MT * 16;
    constexpr int BN = WC * NT * 16;
    constexpr int CA = BM / 64;
    constexpr int CB = BN / 64;
    __shared__ unsigned short As[2][BM * 32];
    __shared__ unsigned short Bs[2][BN * 32];

    const int tid  = threadIdx.x;
    const int lane = tid & 63;
    const int w    = tid >> 6;
    const int wr   = w / WC, wc = w % WC;
    const int quad = lane >> 4;
    const int l15  = lane & 15;
    const int n0   = blockIdx.x * BN;
    const int m0   = blockIdx.y * BM;

    f32x4 acc[MT][NT];
#pragma unroll
    for (int i = 0; i < MT; i++)
#pragma unroll
        for (int j = 0; j < NT; j++) acc[i][j] = (f32x4){0.f, 0.f, 0.f, 0.f};

    auto stage = [&](int k0, int bufi) {
#pragma unroll
        for (int i = 0; i < CA; i++) {
            const int c = tid + i * 256;
            async_cp16(&A[(size_t)(m0 + (c >> 2)) * lda + k0 + (c & 3) * 8], &As[bufi][c * 8]);
        }
#pragma unroll
        for (int i = 0; i < CB; i++) {
            const int c = tid + i * 256;
            async_cp16(&Bt[(size_t)(n0 + (c >> 2)) * ldb + k0 + (c & 3) * 8], &Bs[bufi][c * 8]);
        }
    };

    stage(0, 0);
    const int niter = K >> 5;
    for (int ii = 0; ii < niter; ii++) {
        const int knext = (ii + 1 < niter) ? (ii + 1) * 32 : 0;
        stage(knext, (ii + 1) & 1);
        __builtin_amdgcn_s_waitcnt(0x0f70 | (CA + CB));
        __builtin_amdgcn_s_barrier();

        const unsigned short* Ac = &As[ii & 1][0];
        const unsigned short* Bc = &Bs[ii & 1][0];
        bf16x8 af[MT], bfr[NT];
#pragma unroll
        for (int t = 0; t < MT; t++)
            af[t]  = *(const bf16x8*)&Ac[(wr * MT * 16 + t * 16 + l15) * 32 + quad * 8];
#pragma unroll
        for (int t = 0; t < NT; t++)
            bfr[t] = *(const bf16x8*)&Bc[(wc * NT * 16 + t * 16 + l15) * 32 + quad * 8];
#pragma unroll
        for (int mt = 0; mt < MT; mt++)
#pragma unroll
            for (int nt = 0; nt < NT; nt++)
                acc[mt][nt] = __builtin_amdgcn_mfma_f32_16x16x32_bf16(
                    af[mt], bfr[nt], acc[mt][nt], 0, 0, 0);
        __builtin_amdgcn_s_barrier();
    }

    // ---- epilogue: C/D layout col=lane&15, row=quad*4+reg
    if (QKVW && n0 >= 1024) {
        // V columns: write transposed into vt. Lane holds 4 consecutive s
        // (rows) for a fixed dk -> one aligned 8B store per (mt,nt).
#pragma unroll
        for (int mt = 0; mt < MT; mt++) {
            const int rowb = m0 + wr * MT * 16 + mt * 16 + quad * 4;
            const int bb   = rowb >> 11;        // batch (2048 rows each)
            const int s0   = rowb & 2047;
#pragma unroll
            for (int nt = 0; nt < NT; nt++) {
                const int col = n0 + wc * NT * 16 + nt * 16 + l15;
                const int hh  = (col - 1024) >> 6;
                const int dk  = (col - 1024) & 63;
                const float bv = bias[col];
                short4 pk4;
                pk4.x = (short)f2b(acc[mt][nt][0] + bv);
                pk4.y = (short)f2b(acc[mt][nt][1] + bv);
                pk4.z = (short)f2b(acc[mt][nt][2] + bv);
                pk4.w = (short)f2b(acc[mt][nt][3] + bv);
                *(short4*)(vtout + ((size_t)((bb * 8 + hh) * 64 + dk)) * S_ + s0) = pk4;
            }
        }
        return;
    }
#pragma unroll
    for (int mt = 0; mt < MT; mt++) {
        const int rowb = m0 + wr * MT * 16 + mt * 16 + quad * 4;
#pragma unroll
        for (int nt = 0; nt < NT; nt++) {
            const int col = n0 + wc * NT * 16 + nt * 16 + l15;
            const float bv = HASBIAS ? bias[col] : 0.f;
#pragma unroll
            for (int r = 0; r < 4; r++) {
                const size_t idx = (size_t)(rowb + r) * ldc + col;
                float v = acc[mt][nt][r] + bv;
                if (RESADD == 1) v += ((const float*)RES)[idx];
                if (RESADD == 2) v += b2f(((const unsigned short*)RES)[idx]);
                if (RELU)   v = fmaxf(v, 0.f);
                if (OUTB) ((unsigned short*)Cv)[idx] = f2b(v);
                else      ((float*)Cv)[idx] = v;
            }
        }
    }
}

// ---------------------------------------------------------------------------
// Causal flash attention, REGISTER-P (r11 structure — best measured).
// BQ=64 (4 waves x 16q), KB=64, double-buffered staging + raw barriers.
// S^T trick (A=K,B=Q); PV A-fragment assembled via cross-quad shuffles.
// qk buffer is [M][1024] = q(512)|k(512). Grid 1024 LPT.
// LDS 32 KB + VGPR 48 -> 5 blocks/CU (launch_bounds waves/EU=5).
// ---------------------------------------------------------------------------
__global__ __launch_bounds__(256, 5)
void attn_mfma(const unsigned short* __restrict__ qk,
               const unsigned short* __restrict__ vt,
               unsigned short* __restrict__ ctx)
{
    __shared__ unsigned short Ks[2][64 * 64];   // [kr][d], chunk^=(kr&7)
    __shared__ unsigned short Vs[2][64 * 64];   // [dk][kr], chunk^=(dk&7)

    const int tid  = threadIdx.x;
    const int lane = tid & 63;
    const int w    = tid >> 6;
    const int quad = lane >> 4;
    const int l15  = lane & 15;
    const int bid  = blockIdx.x;
    const int qb   = 31 - (bid >> 5);           // LPT: heaviest first
    const int bh   = bid & 31;
    const int b    = bh >> 3, hh = bh & 7;

    const unsigned short* qbase = qk + (size_t)(b * S_) * 1024 + hh * 64;
    const unsigned short* kbase = qbase + 512;
    const unsigned short* vtb   = vt + (size_t)bh * 64 * S_;

    const int srcA  = 32 * (quad & 1) + l15;    // shuffle sources (same l15)
    const int srcB  = srcA + 16;
    const bool selHi = (quad >> 1) != 0;        // pick tile kc*2+1

    bf16x8 ones;
#pragma unroll
    for (int j = 0; j < 8; j++) ones[j] = (short)0x3F80;

    auto stage = [&](int kb, int bufi) {
        unsigned short* kd = &Ks[bufi][0];
        unsigned short* vd = &Vs[bufi][0];
#pragma unroll
        for (int i = 0; i < 2; i++) {
            const int c = tid + i * 256;
            const int row = c >> 3;
            const int l = (c & 7) ^ (row & 7);
            async_cp16(kbase + (size_t)(kb * 64 + row) * 1024 + l * 8, kd + c * 8);
            async_cp16(vtb + (size_t)row * S_ + kb * 64 + l * 8, vd + c * 8);
        }
    };

    const int qrow0 = qb * 64 + w * 16;
    bf16x8 qf[2];
    {
        const unsigned short* qr = qbase + (size_t)(qrow0 + l15) * 1024;
        qf[0] = *(const bf16x8*)(qr + quad * 8);
        qf[1] = *(const bf16x8*)(qr + 32 + quad * 8);
    }

    f32x4 Oacc[5];
#pragma unroll
    for (int i = 0; i < 5; i++) Oacc[i] = (f32x4){0.f, 0.f, 0.f, 0.f};

    stage(0, 0);

    // PV step for one kc chunk from packed S^T tiles
    auto pv_chunk = [&](const unsigned pk[4][2], int kc, const unsigned short* Vc) {
        const unsigned tA0 = __shfl(pk[kc * 2][0],     srcA, 64);
        const unsigned tA1 = __shfl(pk[kc * 2][1],     srcA, 64);
        const unsigned tB0 = __shfl(pk[kc * 2 + 1][0], srcA, 64);
        const unsigned tB1 = __shfl(pk[kc * 2 + 1][1], srcA, 64);
        const unsigned uA0 = __shfl(pk[kc * 2][0],     srcB, 64);
        const unsigned uA1 = __shfl(pk[kc * 2][1],     srcB, 64);
        const unsigned uB0 = __shfl(pk[kc * 2 + 1][0], srcB, 64);
        const unsigned uB1 = __shfl(pk[kc * 2 + 1][1], srcB, 64);
        u32x4 a;
        a[0] = selHi ? tB0 : tA0;
        a[1] = selHi ? tB1 : tA1;
        a[2] = selHi ? uB0 : uA0;
        a[3] = selHi ? uB1 : uA1;
        const bf16x8 af = __builtin_bit_cast(bf16x8, a);
#pragma unroll
        for (int nt = 0; nt < 4; nt++) {
            const int phys = (kc * 4 + quad) ^ (l15 & 7);
            const bf16x8 vf = *(const bf16x8*)&Vc[(nt * 16 + l15) * 64 + phys * 8];
            Oacc[nt] = __builtin_amdgcn_mfma_f32_16x16x32_bf16(af, vf, Oacc[nt], 0, 0, 0);
        }
        Oacc[4] = __builtin_amdgcn_mfma_f32_16x16x32_bf16(af, ones, Oacc[4], 0, 0, 0);
    };

    // ---- main loop (kb < qb): no masking
    for (int kb = 0; kb < qb; kb++) {
        stage(kb + 1, (kb + 1) & 1);
        __builtin_amdgcn_s_waitcnt(0x0F74);     // vmcnt(4): current tile done
        __builtin_amdgcn_s_barrier();
        const unsigned short* Kc = &Ks[kb & 1][0];
        const unsigned short* Vc = &Vs[kb & 1][0];

        f32x4 st[4];
#pragma unroll
        for (int nt = 0; nt < 4; nt++) st[nt] = (f32x4){0.f, 0.f, 0.f, 0.f};
#pragma unroll
        for (int kc = 0; kc < 2; kc++)
#pragma unroll
            for (int nt = 0; nt < 4; nt++) {
                const int phys = (kc * 4 + quad) ^ (l15 & 7);
                const bf16x8 kf = *(const bf16x8*)&Kc[(nt * 16 + l15) * 64 + phys * 8];
                st[nt] = __builtin_amdgcn_mfma_f32_16x16x32_bf16(kf, qf[kc], st[nt], 0, 0, 0);
            }

        unsigned pk[4][2];
#pragma unroll
        for (int nt = 0; nt < 4; nt++) {
            pk[nt][0] = packbf(exp2f(st[nt][0]), exp2f(st[nt][1]));
            pk[nt][1] = packbf(exp2f(st[nt][2]), exp2f(st[nt][3]));
        }

        pv_chunk(pk, 0, Vc);
        pv_chunk(pk, 1, Vc);
        __builtin_amdgcn_s_barrier();           // reads done before re-stage
    }

    // ---- peeled diagonal iteration (kb == qb), masked
    {
        stage(0, (qb + 1) & 1);                 // dummy prefetch (vmcnt uniform)
        __builtin_amdgcn_s_waitcnt(0x0F74);
        __builtin_amdgcn_s_barrier();
        const unsigned short* Kc = &Ks[qb & 1][0];
        const unsigned short* Vc = &Vs[qb & 1][0];

        f32x4 st[4];
#pragma unroll
        for (int nt = 0; nt < 4; nt++) st[nt] = (f32x4){0.f, 0.f, 0.f, 0.f};
#pragma unroll
        for (int kc = 0; kc < 2; kc++)
#pragma unroll
            for (int nt = 0; nt < 4; nt++) {
                if (nt > w) continue;           // fully-masked key tiles
                const int phys = (kc * 4 + quad) ^ (l15 & 7);
                const bf16x8 kf = *(const bf16x8*)&Kc[(nt * 16 + l15) * 64 + phys * 8];
                st[nt] = __builtin_amdgcn_mfma_f32_16x16x32_bf16(kf, qf[kc], st[nt], 0, 0, 0);
            }

        const int rhs = w * 16 + l15;           // local q row
        unsigned pk[4][2];
#pragma unroll
        for (int nt = 0; nt < 4; nt++) {
            const int kb0 = nt * 16 + quad * 4; // local k of reg 0
            float p[4];
#pragma unroll
            for (int r = 0; r < 4; r++) {
                float s = st[nt][r];
                if (kb0 + r > rhs) s = -1.0e9f; // exp2 -> 0
                p[r] = exp2f(s);
            }
            pk[nt][0] = packbf(p[0], p[1]);
            pk[nt][1] = packbf(p[2], p[3]);
        }

        const int kc_d = (w >> 1) + 1;
        pv_chunk(pk, 0, Vc);
        if (kc_d > 1) pv_chunk(pk, 1, Vc);
    }

    // ---- normalize + write ctx bf16 (O layout: row q=quad*4+r, col dk)
    const int orow = qrow0 + quad * 4;
    unsigned short* cb = ctx + (size_t)(b * S_) * 512 + hh * 64;
#pragma unroll
    for (int r = 0; r < 4; r++) {
        const float inv = 1.f / Oacc[4][r];     // ones-column: all lanes equal
#pragma unroll
        for (int nt = 0; nt < 4; nt++)
            cb[(size_t)(orow + r) * 512 + nt * 16 + l15] = f2b(Oacc[nt][r] * inv);
    }
}

// ---------------------------------------------------------------------------
// LayerNorm: WF -> fp32 out, WB -> bf16 out. 1 wave/row.
// ---------------------------------------------------------------------------
template<int WF, int WB>
__global__ __launch_bounds__(256)
void ln_kernel(const float* __restrict__ s, const float* __restrict__ g,
               const float* __restrict__ be, float* __restrict__ out,
               unsigned short* __restrict__ outb)
{
    const int wave = threadIdx.x >> 6;
    const int lane = threadIdx.x & 63;
    const int row  = blockIdx.x * 4 + wave;
    const float* ps = s + (size_t)row * D_;
    const int c0 = lane * 4;

    float v[8];
    {
        const float4 a0 = *(const float4*)(ps + c0);
        const float4 a1 = *(const float4*)(ps + c0 + 256);
        v[0] = a0.x; v[1] = a0.y; v[2] = a0.z; v[3] = a0.w;
        v[4] = a1.x; v[5] = a1.y; v[6] = a1.z; v[7] = a1.w;
    }

    float sum = 0.f;
#pragma unroll
    for (int i = 0; i < 8; i++) sum += v[i];
#pragma unroll
    for (int m = 1; m < 64; m <<= 1) sum += __shfl_xor(sum, m);
    const float mu = sum * (1.f / D_);

    float sq = 0.f;
#pragma unroll
    for (int i = 0; i < 8; i++) { const float d = v[i] - mu; sq += d * d; }
#pragma unroll
    for (int m = 1; m < 64; m <<= 1) sq += __shfl_xor(sq, m);
    const float rstd = rsqrtf(sq * (1.f / D_) + EPS_);

    const float4 g0 = *(const float4*)(g + c0);
    const float4 b0 = *(const float4*)(be + c0);
    const float4 g1 = *(const float4*)(g + c0 + 256);
    const float4 b1 = *(const float4*)(be + c0 + 256);

    float o[8];
    o[0] = (v[0] - mu) * rstd * g0.x + b0.x;
    o[1] = (v[1] - mu) * rstd * g0.y + b0.y;
    o[2] = (v[2] - mu) * rstd * g0.z + b0.z;
    o[3] = (v[3] - mu) * rstd * g0.w + b0.w;
    o[4] = (v[4] - mu) * rstd * g1.x + b1.x;
    o[5] = (v[5] - mu) * rstd * g1.y + b1.y;
    o[6] = (v[6] - mu) * rstd * g1.z + b1.z;
    o[7] = (v[7] - mu) * rstd * g1.w + b1.w;

    if (WF) {
        *(float4*)(out + (size_t)row * D_ + c0)       = *(float4*)&o[0];
        *(float4*)(out + (size_t)row * D_ + c0 + 256) = *(float4*)&o[4];
    }
    if (WB) {
        short4 vb0 = (short4){(short)f2b(o[0]), (short)f2b(o[1]), (short)f2b(o[2]), (short)f2b(o[3])};
        short4 vb1 = (short4){(short)f2b(o[4]), (short)f2b(o[5]), (short)f2b(o[6]), (short)f2b(o[7])};
        *(short4*)(outb + (size_t)row * D_ + c0)       = vb0;
        *(short4*)(outb + (size_t)row * D_ + c0 + 256) = vb1;
    }
}

// ---------------------------------------------------------------------------
extern "C" void kernel_launch(void* const* d_in, const int* in_sizes, int n_in,
                              void* d_out, int out_size, void* d_ws, size_t ws_size,
                              hipStream_t stream)
{
    const float* x  = (const float*)d_in[0];
    const float* wq = (const float*)d_in[2];
    const float* bq = (const float*)d_in[3];
    const float* wk = (const float*)d_in[4];
    const float* bk = (const float*)d_in[5];
    const float* wv = (const float*)d_in[6];
    const float* bv = (const float*)d_in[7];
    const float* wo = (const float*)d_in[8];
    const float* bo = (const float*)d_in[9];
    const float* w1 = (const float*)d_in[10];
    const float* b1 = (const float*)d_in[11];
    const float* w2 = (const float*)d_in[12];
    const float* b2 = (const float*)d_in[13];
    const float* g1 = (const float*)d_in[14];
    const float* be1= (const float*)d_in[15];
    const float* g2 = (const float*)d_in[16];
    const float* be2= (const float*)d_in[17];
    float* out = (float*)d_out;

    const size_t MB = 1048576;
    char* w8 = (char*)d_ws;
    unsigned short* wqkvt = (unsigned short*)(w8 + 0);            // 1536x512 bf16
    unsigned short* wot   = (unsigned short*)(w8 + 1572864);      // 512x512
    unsigned short* w1t   = (unsigned short*)(w8 + 2097152);      // 2048x512
    unsigned short* w2t   = (unsigned short*)(w8 + 4194304);      // 512x2048
    float*          bqkv  = (float*)(w8 + 6291456);               // 1536 f32
    unsigned short* qk    = (unsigned short*)(w8 + 8 * MB);       // 16 MB [M][1024] (later ffn1b 32MB)
    unsigned short* ffn1b = qk;
    unsigned short* xb    = (unsigned short*)(w8 + 40 * MB);      // 8 MB (later ctx)
    unsigned short* ctx   = xb;
    unsigned short* vt    = (unsigned short*)(w8 + 48 * MB);      // 8 MB (later hb)
    unsigned short* hb    = vt;
    float*          pre   = (float*)(w8 + 56 * MB);               // 16 MB

    const dim3 blk(256);

    // unified preprocessing (1 dispatch)
    prep_kernel<<<dim3(5120), blk, 0, stream>>>(
        x, wq, wk, wv, wo, bq, bk, bv, w1, w2, xb, wqkvt, wot, w1t, w2t, bqkv);

    // qkv GEMM: q|k -> qk [M][1024]; V columns written transposed into vt
    gemm_bf16<2,2,4,4,1,0,0,1,1><<<dim3(12, 64), blk, 0, stream>>>(
        xb, wqkvt, bqkv, nullptr, qk, vt, 512, 512, 512, 1024);

    // causal flash attention (register-P, 1024-block LPT) -> ctx bf16
    attn_mfma<<<dim3(1024), blk, 0, stream>>>(qk, vt, ctx);

    // pre = x + ctx @ wo + bo (fp32 residual)
    gemm_bf16<2,2,2,4,0,0,1,1,0><<<dim3(4, 128), blk, 0, stream>>>(
        ctx, wot, bo, x, pre, nullptr, 512, 512, 512, 512);

    // hb = LN(pre) bf16 only
    ln_kernel<0,1><<<dim3(M_ / 4), blk, 0, stream>>>(pre, g1, be1, nullptr, hb);

    // ffn1 = relu(hb @ w1 + b1) -> bf16 [M][2048]
    gemm_bf16<2,2,4,4,1,1,0,1,0><<<dim3(16, 64), blk, 0, stream>>>(
        hb, w1t, b1, nullptr, ffn1b, nullptr, 512, 512, 512, 2048);

    // pre = hb + ffn1 @ w2 + b2 (bf16 residual)
    gemm_bf16<2,2,2,4,0,0,2,1,0><<<dim3(4, 128), blk, 0, stream>>>(
        ffn1b, w2t, b2, hb, pre, nullptr, 2048, 2048, 2048, 512);

    // out = LN(pre)
    ln_kernel<1,0><<<dim3(M_ / 4), blk, 0, stream>>>(pre, g2, be2, out, nullptr);
}

// Round 14
// 282.612 us; speedup vs baseline: 1.0461x; 1.0383x over previous
//
#include <hip/hip_runtime.h>
#include <math.h>

#define D_   512
#define H_   8
#define DK_  64
#define FF_  2048
#define S_   2048
#define B_   4
#define M_   (B_*S_)     // 8192
#define EPS_ 1e-5f
#define SCLQ 0.1803368801111f   // 0.125 * log2(e): folded into wq/bq at prep

typedef __attribute__((ext_vector_type(8))) short bf16x8;
typedef __attribute__((ext_vector_type(4))) float f32x4;
typedef __attribute__((ext_vector_type(4))) unsigned int u32x4;

__device__ inline unsigned short f2b(float f) {
    unsigned u = __builtin_bit_cast(unsigned, f);
    unsigned r = (u + 0x7FFFu + ((u >> 16) & 1u)) >> 16;
    return (unsigned short)r;
}
__device__ inline float b2f(unsigned short u) {
    return __builtin_bit_cast(float, (unsigned)u << 16);
}
// pack hi16(p0) low half, hi16(p1) high half (truncating bf16 pair)
__device__ inline unsigned packbf(float p0, float p1) {
    return (__builtin_bit_cast(unsigned, p1) & 0xFFFF0000u) |
           (__builtin_bit_cast(unsigned, p0) >> 16);
}

// async 16B global->LDS. LDS dest must be wave-uniform base + lane*16.
__device__ __forceinline__ void async_cp16(const void* g, void* l) {
    __builtin_amdgcn_global_load_lds(
        (const __attribute__((address_space(1))) unsigned int*)g,
        (__attribute__((address_space(3))) unsigned int*)l, 16, 0, 0);
}

// ---------------------------------------------------------------------------
// Unified preprocessing (1 dispatch, 5120 blocks).
// ---------------------------------------------------------------------------
__global__ __launch_bounds__(256)
void prep_kernel(const float* __restrict__ x,
                 const float* __restrict__ wq, const float* __restrict__ wk,
                 const float* __restrict__ wv, const float* __restrict__ wo,
                 const float* __restrict__ bq, const float* __restrict__ bk,
                 const float* __restrict__ bv,
                 const float* __restrict__ w1, const float* __restrict__ w2,
                 unsigned short* __restrict__ xb, unsigned short* __restrict__ wqkvt,
                 unsigned short* __restrict__ wot, unsigned short* __restrict__ w1t,
                 unsigned short* __restrict__ w2t, float* __restrict__ bqkv)
{
    __shared__ float L[32][33];
    const int bid = blockIdx.x;
    const int tid = threadIdx.x;

    if (bid < 2048) {                       // x -> xb
        const int i = (bid * 256 + tid) * 8;
        const float4 a = *(const float4*)(x + i);
        const float4 b = *(const float4*)(x + i + 4);
        bf16x8 v;
        v[0] = (short)f2b(a.x); v[1] = (short)f2b(a.y);
        v[2] = (short)f2b(a.z); v[3] = (short)f2b(a.w);
        v[4] = (short)f2b(b.x); v[5] = (short)f2b(b.y);
        v[6] = (short)f2b(b.z); v[7] = (short)f2b(b.w);
        *(bf16x8*)(xb + i) = v;
        return;
    }

    const float* w; unsigned short* wt; int K, N, k0, n0; float scl = 1.f;
    if (bid < 3072) {
        const int z = (bid - 2048) >> 8;
        const int r = (bid - 2048) & 255;
        n0 = (r & 15) * 32; k0 = (r >> 4) * 32; K = 512; N = 512;
        w  = (z == 0) ? wq : (z == 1) ? wk : (z == 2) ? wv : wo;
        wt = (z < 3) ? (wqkvt + (size_t)z * 512 * 512) : wot;
        if (z == 0) scl = SCLQ;
        if (z < 3 && r == 0) {
            const float* bsrc = (z == 0) ? bq : (z == 1) ? bk : bv;
            const float bscl  = (z == 0) ? SCLQ : 1.f;
            bqkv[z * 512 + tid]       = bsrc[tid] * bscl;
            bqkv[z * 512 + 256 + tid] = bsrc[256 + tid] * bscl;
        }
    } else if (bid < 4096) {
        const int r = bid - 3072;
        n0 = (r & 63) * 32; k0 = (r >> 6) * 32; K = 512; N = 2048;
        w = w1; wt = w1t;
    } else {
        const int r = bid - 4096;
        n0 = (r & 15) * 32; k0 = (r >> 4) * 32; K = 2048; N = 512;
        w = w2; wt = w2t;
    }

    const int xx = tid & 31, y = tid >> 5;
#pragma unroll
    for (int i = 0; i < 4; i++)
        L[y + i * 8][xx] = w[(size_t)(k0 + y + i * 8) * N + n0 + xx] * scl;
    __syncthreads();
#pragma unroll
    for (int i = 0; i < 4; i++)
        wt[(size_t)(n0 + y + i * 8) * K + k0 + xx] = f2b(L[xx][y + i * 8]);
}

// ---------------------------------------------------------------------------
// bf16 MFMA GEMM, double-buffered (prefetch + partial vmcnt + raw s_barrier).
// RESADD: 0 none, 1 fp32 residual, 2 bf16 residual (C-layout indexed).
// ---------------------------------------------------------------------------
template<int WR, int WC, int MT, int NT, int OUTB, int RELU, int RESADD, int HASBIAS>
__global__ __launch_bounds__(256)
void gemm_bf16(const unsigned short* __restrict__ A, const unsigned short* __restrict__ Bt,
               const float* __restrict__ bias, const void* __restrict__ RES,
               void* __restrict__ Cv, int K, int lda, int ldb, int ldc)
{
    constexpr int BM = WR * MT * 16;
    constexpr int BN = WC * NT * 16;
    constexpr int CA = BM / 64;
    constexpr int CB = BN / 64;
    __shared__ unsigned short As[2][BM * 32];
    __shared__ unsigned short Bs[2][BN * 32];

    const int tid  = threadIdx.x;
    const int lane = tid & 63;
    const int w    = tid >> 6;
    const int wr   = w / WC, wc = w % WC;
    const int quad = lane >> 4;
    const int l15  = lane & 15;
    const int n0   = blockIdx.x * BN;
    const int m0   = blockIdx.y * BM;

    f32x4 acc[MT][NT];
#pragma unroll
    for (int i = 0; i < MT; i++)
#pragma unroll
        for (int j = 0; j < NT; j++) acc[i][j] = (f32x4){0.f, 0.f, 0.f, 0.f};

    auto stage = [&](int k0, int bufi) {
#pragma unroll
        for (int i = 0; i < CA; i++) {
            const int c = tid + i * 256;
            async_cp16(&A[(size_t)(m0 + (c >> 2)) * lda + k0 + (c & 3) * 8], &As[bufi][c * 8]);
        }
#pragma unroll
        for (int i = 0; i < CB; i++) {
            const int c = tid + i * 256;
            async_cp16(&Bt[(size_t)(n0 + (c >> 2)) * ldb + k0 + (c & 3) * 8], &Bs[bufi][c * 8]);
        }
    };

    stage(0, 0);
    const int niter = K >> 5;
    for (int ii = 0; ii < niter; ii++) {
        const int knext = (ii + 1 < niter) ? (ii + 1) * 32 : 0;
        stage(knext, (ii + 1) & 1);
        __builtin_amdgcn_s_waitcnt(0x0f70 | (CA + CB));
        __builtin_amdgcn_s_barrier();

        const unsigned short* Ac = &As[ii & 1][0];
        const unsigned short* Bc = &Bs[ii & 1][0];
        bf16x8 af[MT], bfr[NT];
#pragma unroll
        for (int t = 0; t < MT; t++)
            af[t]  = *(const bf16x8*)&Ac[(wr * MT * 16 + t * 16 + l15) * 32 + quad * 8];
#pragma unroll
        for (int t = 0; t < NT; t++)
            bfr[t] = *(const bf16x8*)&Bc[(wc * NT * 16 + t * 16 + l15) * 32 + quad * 8];
#pragma unroll
        for (int mt = 0; mt < MT; mt++)
#pragma unroll
            for (int nt = 0; nt < NT; nt++)
                acc[mt][nt] = __builtin_amdgcn_mfma_f32_16x16x32_bf16(
                    af[mt], bfr[nt], acc[mt][nt], 0, 0, 0);
        __builtin_amdgcn_s_barrier();
    }

    // epilogue: C/D layout col=lane&15, row=quad*4+reg
#pragma unroll
    for (int mt = 0; mt < MT; mt++) {
        const int rowb = m0 + wr * MT * 16 + mt * 16 + quad * 4;
#pragma unroll
        for (int nt = 0; nt < NT; nt++) {
            const int col = n0 + wc * NT * 16 + nt * 16 + l15;
            const float bv = HASBIAS ? bias[col] : 0.f;
#pragma unroll
            for (int r = 0; r < 4; r++) {
                const size_t idx = (size_t)(rowb + r) * ldc + col;
                float v = acc[mt][nt][r] + bv;
                if (RESADD == 1) v += ((const float*)RES)[idx];
                if (RESADD == 2) v += b2f(((const unsigned short*)RES)[idx]);
                if (RELU)   v = fmaxf(v, 0.f);
                if (OUTB) ((unsigned short*)Cv)[idx] = f2b(v);
                else      ((float*)Cv)[idx] = v;
            }
        }
    }
}

// ---------------------------------------------------------------------------
// V transpose: qkv v-part [s][dk] per (b,h) -> vt [(b*8+h)*64+dk][s] bf16.
// ---------------------------------------------------------------------------
__global__ __launch_bounds__(256)
void vtrans(const unsigned short* __restrict__ qkv, unsigned short* __restrict__ vt)
{
    __shared__ unsigned short L[64][72];
    const int s0 = blockIdx.x * 64;
    const int bh = blockIdx.y;
    const int b  = bh >> 3, hh = bh & 7;
    const int tid = threadIdx.x;
    const unsigned short* src = qkv + (size_t)(b * S_) * 1536 + 1024 + hh * 64;
#pragma unroll
    for (int i = 0; i < 2; i++) {
        const int c = tid + i * 256;
        const int r = c >> 3, sub = (c & 7) * 8;
        *(bf16x8*)&L[r][sub] = *(const bf16x8*)(src + (size_t)(s0 + r) * 1536 + sub);
    }
    __syncthreads();
    const int dk = tid >> 2;
    const int sc = (tid & 3) * 16;
    bf16x8 t0, t1;
#pragma unroll
    for (int j = 0; j < 8; j++) t0[j] = (short)L[sc + j][dk];
#pragma unroll
    for (int j = 0; j < 8; j++) t1[j] = (short)L[sc + 8 + j][dk];
    unsigned short* dst = vt + (size_t)(bh * 64 + dk) * S_ + s0 + sc;
    *(bf16x8*)(dst)     = t0;
    *(bf16x8*)(dst + 8) = t1;
}

// ---------------------------------------------------------------------------
// Causal flash attention, K-SPLIT register-P. BQ=64, KB=64, grid 1024 LPT.
// Wave w owns k-chunk kh=w&1 (32 keys) x q-half qh=w>>1 (32 queries):
// kf reads 4/iter (vs 8), vf reads 4/iter shared across both q-tiles (vs 8)
// -> block DS-read traffic HALVES (the measured residual bottleneck).
// No-max softmax => O is a pure sum: per-wave partial O over its k-chunk,
// summed once at the end via LDS (waves kh=1 -> kh=0 of same q-half).
// S^T trick (A=K,B=Q); PV A-frag assembled via cross-quad shuffles.
// Diagonal peel: wave(k1,q0) fully masked (skip); waves(k0,q0),(k1,q1) share
// local triangle predicate quad*4+r > l15; wave(k0,q1) unmasked.
// ---------------------------------------------------------------------------
__global__ __launch_bounds__(256, 4)
void attn_mfma(const unsigned short* __restrict__ qkv,
               const unsigned short* __restrict__ vt,
               unsigned short* __restrict__ ctx)
{
    __shared__ unsigned short Ks[2][64 * 64];   // [kr][d], chunk^=(kr&7)
    __shared__ unsigned short Vs[2][64 * 64];   // [dk][kr], chunk^=(dk&7)

    const int tid  = threadIdx.x;
    const int lane = tid & 63;
    const int w    = tid >> 6;
    const int quad = lane >> 4;
    const int l15  = lane & 15;
    const int bid  = blockIdx.x;
    const int qb   = 31 - (bid >> 5);           // LPT: heaviest first
    const int bh   = bid & 31;
    const int b    = bh >> 3, hh = bh & 7;
    const int kh   = w & 1;                     // k-chunk (32 keys)
    const int qh   = w >> 1;                    // q-half (32 queries)

    const unsigned short* qbase = qkv + (size_t)(b * S_) * 1536 + hh * 64;
    const unsigned short* kbase = qbase + 512;
    const unsigned short* vtb   = vt + (size_t)bh * 64 * S_;

    const int srcA  = 32 * (quad & 1) + l15;    // shuffle sources (same q col)
    const int srcB  = srcA + 16;
    const bool selHi = (quad >> 1) != 0;        // target k 16..31 -> tile kt=1

    bf16x8 ones;
#pragma unroll
    for (int j = 0; j < 8; j++) ones[j] = (short)0x3F80;

    auto stage = [&](int kb, int bufi) {
        unsigned short* kd = &Ks[bufi][0];
        unsigned short* vd = &Vs[bufi][0];
#pragma unroll
        for (int i = 0; i < 2; i++) {
            const int c = tid + i * 256;
            const int row = c >> 3;
            const int l = (c & 7) ^ (row & 7);
            async_cp16(kbase + (size_t)(kb * 64 + row) * 1536 + l * 8, kd + c * 8);
            async_cp16(vtb + (size_t)row * S_ + kb * 64 + l * 8, vd + c * 8);
        }
    };

    // Q fragments: 2 q-tiles x 2 kc (d chunks)
    bf16x8 qf[2][2];
#pragma unroll
    for (int qt = 0; qt < 2; qt++) {
        const unsigned short* qr = qbase + (size_t)(qb * 64 + qh * 32 + qt * 16 + l15) * 1536;
        qf[qt][0] = *(const bf16x8*)(qr + quad * 8);
        qf[qt][1] = *(const bf16x8*)(qr + 32 + quad * 8);
    }

    f32x4 Oacc[2][5];                           // [qt][0..3]=O dk-tiles, [4]=row-sum
#pragma unroll
    for (int qt = 0; qt < 2; qt++)
#pragma unroll
        for (int i = 0; i < 5; i++) Oacc[qt][i] = (f32x4){0.f, 0.f, 0.f, 0.f};

    stage(0, 0);

    // assemble PV A-fragment (32-k chunk) from two S^T tiles (kt0, kt1)
    auto assemble2 = [&](const unsigned t0[2], const unsigned t1[2]) -> bf16x8 {
        const unsigned a0A = __shfl(t0[0], srcA, 64);
        const unsigned a1A = __shfl(t0[1], srcA, 64);
        const unsigned b0A = __shfl(t1[0], srcA, 64);
        const unsigned b1A = __shfl(t1[1], srcA, 64);
        const unsigned a0B = __shfl(t0[0], srcB, 64);
        const unsigned a1B = __shfl(t0[1], srcB, 64);
        const unsigned b0B = __shfl(t1[0], srcB, 64);
        const unsigned b1B = __shfl(t1[1], srcB, 64);
        u32x4 a;
        a[0] = selHi ? b0A : a0A;
        a[1] = selHi ? b1A : a1A;
        a[2] = selHi ? b0B : a0B;
        a[3] = selHi ? b1B : a1B;
        return __builtin_bit_cast(bf16x8, a);
    };

    const int physv = (kh * 4 + quad) ^ (l15 & 7);  // V^T k-offset chunk for this wave

    // ---- main loop (kb < qb): no masking
    for (int kb = 0; kb < qb; kb++) {
        stage(kb + 1, (kb + 1) & 1);
        __builtin_amdgcn_s_waitcnt(0x0F74);     // vmcnt(4): current tile done
        __builtin_amdgcn_s_barrier();
        const unsigned short* Kc = &Ks[kb & 1][0];
        const unsigned short* Vc = &Vs[kb & 1][0];

        f32x4 st[2][2];                         // [qt][kt]
#pragma unroll
        for (int qt = 0; qt < 2; qt++)
#pragma unroll
            for (int kt = 0; kt < 2; kt++) st[qt][kt] = (f32x4){0.f, 0.f, 0.f, 0.f};
#pragma unroll
        for (int kc = 0; kc < 2; kc++) {
            const int phys = (kc * 4 + quad) ^ (l15 & 7);
            const bf16x8 kf0 = *(const bf16x8*)&Kc[(kh * 32 + l15) * 64 + phys * 8];
            const bf16x8 kf1 = *(const bf16x8*)&Kc[(kh * 32 + 16 + l15) * 64 + phys * 8];
#pragma unroll
            for (int qt = 0; qt < 2; qt++) {
                st[qt][0] = __builtin_amdgcn_mfma_f32_16x16x32_bf16(kf0, qf[qt][kc], st[qt][0], 0, 0, 0);
                st[qt][1] = __builtin_amdgcn_mfma_f32_16x16x32_bf16(kf1, qf[qt][kc], st[qt][1], 0, 0, 0);
            }
        }

        unsigned pk[2][2][2];                   // [qt][kt][regpair]
#pragma unroll
        for (int qt = 0; qt < 2; qt++)
#pragma unroll
            for (int kt = 0; kt < 2; kt++) {
                pk[qt][kt][0] = packbf(exp2f(st[qt][kt][0]), exp2f(st[qt][kt][1]));
                pk[qt][kt][1] = packbf(exp2f(st[qt][kt][2]), exp2f(st[qt][kt][3]));
            }

        bf16x8 vf[4];
#pragma unroll
        for (int nt = 0; nt < 4; nt++)
            vf[nt] = *(const bf16x8*)&Vc[(nt * 16 + l15) * 64 + physv * 8];
#pragma unroll
        for (int qt = 0; qt < 2; qt++) {
            const bf16x8 af = assemble2(pk[qt][0], pk[qt][1]);
#pragma unroll
            for (int nt = 0; nt < 4; nt++)
                Oacc[qt][nt] = __builtin_amdgcn_mfma_f32_16x16x32_bf16(af, vf[nt], Oacc[qt][nt], 0, 0, 0);
            Oacc[qt][4] = __builtin_amdgcn_mfma_f32_16x16x32_bf16(af, ones, Oacc[qt][4], 0, 0, 0);
        }
        __builtin_amdgcn_s_barrier();           // reads done before re-stage
    }

    // ---- peeled diagonal iteration (kb == qb)
    {
        stage(0, (qb + 1) & 1);                 // dummy prefetch (vmcnt uniform)
        __builtin_amdgcn_s_waitcnt(0x0F74);
        __builtin_amdgcn_s_barrier();
        const unsigned short* Kc = &Ks[qb & 1][0];
        const unsigned short* Vc = &Vs[qb & 1][0];

        const bool skipDiag = (kh == 1 && qh == 0);   // k 32..63 > q 0..31: all masked
        const bool fullDiag = (kh == 0 && qh == 1);   // k 0..31 < q 32..63: no mask

        if (!skipDiag) {
            f32x4 st[2][2];
#pragma unroll
            for (int qt = 0; qt < 2; qt++)
#pragma unroll
                for (int kt = 0; kt < 2; kt++) st[qt][kt] = (f32x4){0.f, 0.f, 0.f, 0.f};
#pragma unroll
            for (int kc = 0; kc < 2; kc++) {
                const int phys = (kc * 4 + quad) ^ (l15 & 7);
                const bf16x8 kf0 = *(const bf16x8*)&Kc[(kh * 32 + l15) * 64 + phys * 8];
                const bf16x8 kf1 = *(const bf16x8*)&Kc[(kh * 32 + 16 + l15) * 64 + phys * 8];
#pragma unroll
                for (int qt = 0; qt < 2; qt++) {
                    st[qt][0] = __builtin_amdgcn_mfma_f32_16x16x32_bf16(kf0, qf[qt][kc], st[qt][0], 0, 0, 0);
                    st[qt][1] = __builtin_amdgcn_mfma_f32_16x16x32_bf16(kf1, qf[qt][kc], st[qt][1], 0, 0, 0);
                }
            }

            unsigned pk[2][2][2];
            if (fullDiag) {
#pragma unroll
                for (int qt = 0; qt < 2; qt++)
#pragma unroll
                    for (int kt = 0; kt < 2; kt++) {
                        pk[qt][kt][0] = packbf(exp2f(st[qt][kt][0]), exp2f(st[qt][kt][1]));
                        pk[qt][kt][1] = packbf(exp2f(st[qt][kt][2]), exp2f(st[qt][kt][3]));
                    }
            } else {
                // tiles: (qt0,kt0) tri, (qt0,kt1) all-masked, (qt1,kt0) full,
                // (qt1,kt1) tri. tri predicate (local): quad*4+r > l15.
                float p[4];
#pragma unroll
                for (int r = 0; r < 4; r++)
                    p[r] = (quad * 4 + r > l15) ? 0.f : exp2f(st[0][0][r]);
                pk[0][0][0] = packbf(p[0], p[1]);
                pk[0][0][1] = packbf(p[2], p[3]);
                pk[0][1][0] = 0u; pk[0][1][1] = 0u;
                pk[1][0][0] = packbf(exp2f(st[1][0][0]), exp2f(st[1][0][1]));
                pk[1][0][1] = packbf(exp2f(st[1][0][2]), exp2f(st[1][0][3]));
#pragma unroll
                for (int r = 0; r < 4; r++)
                    p[r] = (quad * 4 + r > l15) ? 0.f : exp2f(st[1][1][r]);
                pk[1][1][0] = packbf(p[0], p[1]);
                pk[1][1][1] = packbf(p[2], p[3]);
            }

            bf16x8 vf[4];
#pragma unroll
            for (int nt = 0; nt < 4; nt++)
                vf[nt] = *(const bf16x8*)&Vc[(nt * 16 + l15) * 64 + physv * 8];
#pragma unroll
            for (int qt = 0; qt < 2; qt++) {
                const bf16x8 af = assemble2(pk[qt][0], pk[qt][1]);
#pragma unroll
                for (int nt = 0; nt < 4; nt++)
                    Oacc[qt][nt] = __builtin_amdgcn_mfma_f32_16x16x32_bf16(af, vf[nt], Oacc[qt][nt], 0, 0, 0);
                Oacc[qt][4] = __builtin_amdgcn_mfma_f32_16x16x32_bf16(af, ones, Oacc[qt][4], 0, 0, 0);
            }
        }
    }

    // ---- cross-wave reduction (kh=1 partials -> kh=0), then write ctx
    __syncthreads();
    float* red = (float*)&Ks[0][0];             // 2 regions x 64 lanes x 44 floats = 22 KB
    const int rbase = (qh * 64 + lane) * 44;
    if (kh) {
#pragma unroll
        for (int qt = 0; qt < 2; qt++)
#pragma unroll
            for (int i = 0; i < 5; i++)
                *(f32x4*)&red[rbase + (qt * 5 + i) * 4] = Oacc[qt][i];
    }
    __syncthreads();
    if (!kh) {
#pragma unroll
        for (int qt = 0; qt < 2; qt++)
#pragma unroll
            for (int i = 0; i < 5; i++)
                Oacc[qt][i] += *(const f32x4*)&red[rbase + (qt * 5 + i) * 4];

        unsigned short* cb = ctx + (size_t)(b * S_) * 512 + hh * 64;
#pragma unroll
        for (int qt = 0; qt < 2; qt++) {
            const int orow = qb * 64 + qh * 32 + qt * 16 + quad * 4;
#pragma unroll
            for (int r = 0; r < 4; r++) {
                const float inv = 1.f / Oacc[qt][4][r];
#pragma unroll
                for (int nt = 0; nt < 4; nt++)
                    cb[(size_t)(orow + r) * 512 + nt * 16 + l15] = f2b(Oacc[qt][nt][r] * inv);
            }
        }
    }
}

// ---------------------------------------------------------------------------
// LayerNorm: WF -> fp32 out, WB -> bf16 out. 1 wave/row.
// ---------------------------------------------------------------------------
template<int WF, int WB>
__global__ __launch_bounds__(256)
void ln_kernel(const float* __restrict__ s, const float* __restrict__ g,
               const float* __restrict__ be, float* __restrict__ out,
               unsigned short* __restrict__ outb)
{
    const int wave = threadIdx.x >> 6;
    const int lane = threadIdx.x & 63;
    const int row  = blockIdx.x * 4 + wave;
    const float* ps = s + (size_t)row * D_;
    const int c0 = lane * 4;

    float v[8];
    {
        const float4 a0 = *(const float4*)(ps + c0);
        const float4 a1 = *(const float4*)(ps + c0 + 256);
        v[0] = a0.x; v[1] = a0.y; v[2] = a0.z; v[3] = a0.w;
        v[4] = a1.x; v[5] = a1.y; v[6] = a1.z; v[7] = a1.w;
    }

    float sum = 0.f;
#pragma unroll
    for (int i = 0; i < 8; i++) sum += v[i];
#pragma unroll
    for (int m = 1; m < 64; m <<= 1) sum += __shfl_xor(sum, m);
    const float mu = sum * (1.f / D_);

    float sq = 0.f;
#pragma unroll
    for (int i = 0; i < 8; i++) { const float d = v[i] - mu; sq += d * d; }
#pragma unroll
    for (int m = 1; m < 64; m <<= 1) sq += __shfl_xor(sq, m);
    const float rstd = rsqrtf(sq * (1.f / D_) + EPS_);

    const float4 g0 = *(const float4*)(g + c0);
    const float4 b0 = *(const float4*)(be + c0);
    const float4 g1 = *(const float4*)(g + c0 + 256);
    const float4 b1 = *(const float4*)(be + c0 + 256);

    float o[8];
    o[0] = (v[0] - mu) * rstd * g0.x + b0.x;
    o[1] = (v[1] - mu) * rstd * g0.y + b0.y;
    o[2] = (v[2] - mu) * rstd * g0.z + b0.z;
    o[3] = (v[3] - mu) * rstd * g0.w + b0.w;
    o[4] = (v[4] - mu) * rstd * g1.x + b1.x;
    o[5] = (v[5] - mu) * rstd * g1.y + b1.y;
    o[6] = (v[6] - mu) * rstd * g1.z + b1.z;
    o[7] = (v[7] - mu) * rstd * g1.w + b1.w;

    if (WF) {
        *(float4*)(out + (size_t)row * D_ + c0)       = *(float4*)&o[0];
        *(float4*)(out + (size_t)row * D_ + c0 + 256) = *(float4*)&o[4];
    }
    if (WB) {
        short4 vb0 = (short4){(short)f2b(o[0]), (short)f2b(o[1]), (short)f2b(o[2]), (short)f2b(o[3])};
        short4 vb1 = (short4){(short)f2b(o[4]), (short)f2b(o[5]), (short)f2b(o[6]), (short)f2b(o[7])};
        *(short4*)(outb + (size_t)row * D_ + c0)       = vb0;
        *(short4*)(outb + (size_t)row * D_ + c0 + 256) = vb1;
    }
}

// ---------------------------------------------------------------------------
extern "C" void kernel_launch(void* const* d_in, const int* in_sizes, int n_in,
                              void* d_out, int out_size, void* d_ws, size_t ws_size,
                              hipStream_t stream)
{
    const float* x  = (const float*)d_in[0];
    const float* wq = (const float*)d_in[2];
    const float* bq = (const float*)d_in[3];
    const float* wk = (const float*)d_in[4];
    const float* bk = (const float*)d_in[5];
    const float* wv = (const float*)d_in[6];
    const float* bv = (const float*)d_in[7];
    const float* wo = (const float*)d_in[8];
    const float* bo = (const float*)d_in[9];
    const float* w1 = (const float*)d_in[10];
    const float* b1 = (const float*)d_in[11];
    const float* w2 = (const float*)d_in[12];
    const float* b2 = (const float*)d_in[13];
    const float* g1 = (const float*)d_in[14];
    const float* be1= (const float*)d_in[15];
    const float* g2 = (const float*)d_in[16];
    const float* be2= (const float*)d_in[17];
    float* out = (float*)d_out;

    const size_t MB = 1048576;
    char* w8 = (char*)d_ws;
    unsigned short* wqkvt = (unsigned short*)(w8 + 0);            // 1536x512 bf16
    unsigned short* wot   = (unsigned short*)(w8 + 1572864);      // 512x512
    unsigned short* w1t   = (unsigned short*)(w8 + 2097152);      // 2048x512
    unsigned short* w2t   = (unsigned short*)(w8 + 4194304);      // 512x2048
    float*          bqkv  = (float*)(w8 + 6291456);               // 1536 f32
    unsigned short* qkv   = (unsigned short*)(w8 + 8 * MB);       // 24 MB (later ffn1b)
    unsigned short* ffn1b = qkv;
    unsigned short* xb    = (unsigned short*)(w8 + 40 * MB);      // 8 MB (later ctx)
    unsigned short* ctx   = xb;
    unsigned short* vt    = (unsigned short*)(w8 + 48 * MB);      // 8 MB (later hb)
    unsigned short* hb    = vt;
    float*          pre   = (float*)(w8 + 56 * MB);               // 16 MB

    const dim3 blk(256);

    // unified preprocessing (1 dispatch)
    prep_kernel<<<dim3(5120), blk, 0, stream>>>(
        x, wq, wk, wv, wo, bq, bk, bv, w1, w2, xb, wqkvt, wot, w1t, w2t, bqkv);

    // qkv = xb @ [wq*SCLQ|wk|wv] + b -> bf16 [M][1536]
    gemm_bf16<2,2,4,4,1,0,0,1><<<dim3(12, 64), blk, 0, stream>>>(
        xb, wqkvt, bqkv, nullptr, qkv, 512, 512, 512, 1536);

    vtrans<<<dim3(32, 32), blk, 0, stream>>>(qkv, vt);

    // causal flash attention (k-split register-P, 1024-block LPT) -> ctx bf16
    attn_mfma<<<dim3(1024), blk, 0, stream>>>(qkv, vt, ctx);

    // pre = x + ctx @ wo + bo (fp32 residual)
    gemm_bf16<2,2,2,4,0,0,1,1><<<dim3(4, 128), blk, 0, stream>>>(
        ctx, wot, bo, x, pre, 512, 512, 512, 512);

    // hb = LN(pre) bf16 only
    ln_kernel<0,1><<<dim3(M_ / 4), blk, 0, stream>>>(pre, g1, be1, nullptr, hb);

    // ffn1 = relu(hb @ w1 + b1) -> bf16 [M][2048]
    gemm_bf16<2,2,4,4,1,1,0,1><<<dim3(16, 64), blk, 0, stream>>>(
        hb, w1t, b1, nullptr, ffn1b, 512, 512, 512, 2048);

    // pre = hb + ffn1 @ w2 + b2 (bf16 residual)
    gemm_bf16<2,2,2,4,0,0,2,1><<<dim3(4, 128), blk, 0, stream>>>(
        ffn1b, w2t, b2, hb, pre, 2048, 2048, 2048, 512);

    // out = LN(pre)
    ln_kernel<1,0><<<dim3(M_ / 4), blk, 0, stream>>>(pre, g2, be2, out, nullptr);
}